// Round 6
// baseline (1429.953 us; speedup 1.0000x reference)
//
#include <hip/hip_runtime.h>
#include <math.h>

#define NN 50000
#define MP 50048          // NN padded to multiple of 128 (32 rows x 4 waves)
#define NE 800000
#define FIN 64
#define HD 200
#define NG 256
#define SCAN_B 256
#define KPAD 224          // HD padded: 8 chunks x 28 cols, and multiple of 32 for MFMA
#define NT 13             // 13 * 16 = 208 >= 200 output col tiles

typedef _Float16 h16;
typedef __attribute__((ext_vector_type(8))) _Float16 half8;
typedef __attribute__((ext_vector_type(4))) float float4v;

// ---------- setup: src out-degree (float) + dst in-degree (int, for CSR) ----------
__global__ void k_deg(const int* __restrict__ src, const int* __restrict__ dst,
                      float* __restrict__ deg, int* __restrict__ cnt_dst, int E) {
    int e = blockIdx.x * blockDim.x + threadIdx.x;
    if (e < E) {
        atomicAdd(&deg[src[e]], 1.0f);
        atomicAdd(&cnt_dst[dst[e]], 1);
    }
}

__global__ void k_node_prep(float* __restrict__ degdis, const int* __restrict__ batch,
                            const float* __restrict__ lmax, float* __restrict__ diag, int n) {
    int i = blockIdx.x * blockDim.x + threadIdx.x;
    if (i < n) {
        float d = degdis[i];
        degdis[i] = (d > 0.f) ? (1.0f / sqrtf(fmaxf(d, 1.0f))) : 0.0f;   // dis
        diag[i] = 2.0f / lmax[batch[i]] - 1.0f;
    }
}

// ---------- exclusive scan over cnt_dst ----------
__global__ void k_scan1(const int* __restrict__ cnt, int* __restrict__ excl,
                        int* __restrict__ bsum, int n) {
    __shared__ int sh[SCAN_B];
    int tid = threadIdx.x;
    int i = blockIdx.x * SCAN_B + tid;
    int v = (i < n) ? cnt[i] : 0;
    sh[tid] = v;
    __syncthreads();
    for (int off = 1; off < SCAN_B; off <<= 1) {
        int t = (tid >= off) ? sh[tid - off] : 0;
        __syncthreads();
        sh[tid] += t;
        __syncthreads();
    }
    if (i < n) excl[i] = sh[tid] - v;
    if (tid == SCAN_B - 1) bsum[blockIdx.x] = sh[tid];
}

__global__ void k_scan2(int* __restrict__ bsum, int nb) {
    __shared__ int sh[SCAN_B];
    int tid = threadIdx.x;
    int v = (tid < nb) ? bsum[tid] : 0;
    sh[tid] = v;
    __syncthreads();
    for (int off = 1; off < SCAN_B; off <<= 1) {
        int t = (tid >= off) ? sh[tid - off] : 0;
        __syncthreads();
        sh[tid] += t;
        __syncthreads();
    }
    if (tid < nb) bsum[tid] = sh[tid] - v;   // exclusive
}

__global__ void k_scan3(int* __restrict__ excl, const int* __restrict__ bsum, int n) {
    int i = blockIdx.x * SCAN_B + threadIdx.x;
    if (i < n) excl[i] += bsum[blockIdx.x];
}

// ---------- permute edges into CSR-by-dst order, fused edge-weight compute ----------
__global__ void k_fillcsr(const int* __restrict__ src, const int* __restrict__ dst,
                          const int* __restrict__ batch, const float* __restrict__ lmax,
                          const float* __restrict__ dis, const int* __restrict__ rowstart,
                          int* __restrict__ fill, int* __restrict__ csr_src,
                          float* __restrict__ csr_w, int E) {
    int e = blockIdx.x * blockDim.x + threadIdx.x;
    if (e < E) {
        int s = src[e], d = dst[e];
        int pos = rowstart[d] + atomicAdd(&fill[d], 1);
        csr_src[pos] = s;
        csr_w[pos] = -dis[s] * dis[d] * (2.0f / lmax[batch[s]]);
    }
}

// ---------- fp32 -> fp16 split for x ----------
__global__ void k_split(const float* __restrict__ x, h16* __restrict__ x16, int total) {
    int i = blockIdx.x * blockDim.x + threadIdx.x;
    if (i < total) x16[i] = (h16)x[i];
}

// ---------- W pre-transpose: f32 [3][fin][HD] -> fp16 [seg][ks][208][32] ----------
__global__ void k_wprep(const float* __restrict__ W, h16* __restrict__ out,
                        int fin, int ksteps, int total) {
    int idx = blockIdx.x * blockDim.x + threadIdx.x;
    if (idx >= total) return;
    int kk = idx & 31;
    int r = idx >> 5;
    int nn = r % 208;
    int r2 = r / 208;
    int ks = r2 % ksteps;
    int seg = r2 / ksteps;
    int k = ks * 32 + kk;
    out[idx] = (nn < HD && k < fin) ? (h16)W[((size_t)seg * fin + k) * HD + nn] : (h16)0.f;
}

// ---------- graph boundaries (batch is sorted) ----------
__global__ void k_bounds(const int* __restrict__ batch, int* __restrict__ gstart, int n) {
    int g = blockIdx.x * blockDim.x + threadIdx.x;
    if (g > NG) return;
    if (g == NG) { gstart[NG] = n; return; }
    int lo = 0, hi = n;
    while (lo < hi) {
        int mid = (lo + hi) >> 1;
        if (batch[mid] < g) lo = mid + 1; else hi = mid;
    }
    gstart[g] = lo;
}

// ---------- propagation (gather, fp16, XCD-pinned column chunks) ----------
// chunk = blockIdx.x % nch  -> round-robin workgroup->XCD mapping pins each
// chunk's 50048 x CW working set (2.8 MB at CW=28) into one XCD's 4 MB L2.
// 8-lane group per node, 32 nodes per 256-thr block.
// mode 0: v = gath + diag*hin        mode 1: v = 2*(gath + diag*hin) - hin0
__global__ __launch_bounds__(256) void k_gather(
    const int* __restrict__ rowstart, const int* __restrict__ rowcnt,
    const int* __restrict__ csr_src, const float* __restrict__ csr_w,
    const float* __restrict__ diag, const h16* __restrict__ hin16,
    const h16* __restrict__ h016, h16* __restrict__ hout16,
    int s16, int CW, int nch, int n, int mode) {
    int chunk = blockIdx.x % nch;
    int nb = blockIdx.x / nch;
    int i = nb * 32 + (threadIdx.x >> 3);
    if (i >= n) return;
    int gl = threadIdx.x & 7;
    if (gl * 4 >= CW) return;                      // CW=28 -> 7/8 lanes active
    int c0 = chunk * CW + gl * 4;                  // byte offset 8-aligned (CW*2 % 8 == 0)
    int start = rowstart[i], cnt = rowcnt[i];
    float a0 = 0.f, a1 = 0.f, a2 = 0.f, a3 = 0.f;
    union U { uint2 u; h16 h[4]; };
    int k = 0;
    for (; k + 1 < cnt; k += 2) {
        int s0 = csr_src[start + k], s1 = csr_src[start + k + 1];
        float w0 = csr_w[start + k], w1 = csr_w[start + k + 1];
        U p0, p1;
        p0.u = *(const uint2*)(hin16 + (size_t)s0 * s16 + c0);
        p1.u = *(const uint2*)(hin16 + (size_t)s1 * s16 + c0);
        a0 += w0 * (float)p0.h[0] + w1 * (float)p1.h[0];
        a1 += w0 * (float)p0.h[1] + w1 * (float)p1.h[1];
        a2 += w0 * (float)p0.h[2] + w1 * (float)p1.h[2];
        a3 += w0 * (float)p0.h[3] + w1 * (float)p1.h[3];
    }
    if (k < cnt) {
        int s0 = csr_src[start + k];
        float w0 = csr_w[start + k];
        U p0;
        p0.u = *(const uint2*)(hin16 + (size_t)s0 * s16 + c0);
        a0 += w0 * (float)p0.h[0];
        a1 += w0 * (float)p0.h[1];
        a2 += w0 * (float)p0.h[2];
        a3 += w0 * (float)p0.h[3];
    }
    float dg = diag[i];
    U hs; hs.u = *(const uint2*)(hin16 + (size_t)i * s16 + c0);
    float v0 = a0 + dg * (float)hs.h[0];
    float v1 = a1 + dg * (float)hs.h[1];
    float v2 = a2 + dg * (float)hs.h[2];
    float v3 = a3 + dg * (float)hs.h[3];
    if (mode == 1) {
        U h0; h0.u = *(const uint2*)(h016 + (size_t)i * s16 + c0);
        v0 = 2.f * v0 - (float)h0.h[0];
        v1 = 2.f * v1 - (float)h0.h[1];
        v2 = 2.f * v2 - (float)h0.h[2];
        v3 = 2.f * v3 - (float)h0.h[3];
    }
    U o;
    o.h[0] = (h16)v0; o.h[1] = (h16)v1; o.h[2] = (h16)v2; o.h[3] = (h16)v3;
    *(uint2*)(hout16 + (size_t)i * s16 + c0) = o.u;
}

// ---------- MFMA fp16 GEMM, barrier-free: out = relu([A0|A1|A2] @ W + b) ----------
// Each wave: 32 rows x 208 cols (2 row-frags share each B-fragment -> halves B traffic).
__global__ __launch_bounds__(256) void k_gemm16(
    const h16* __restrict__ A0, const h16* __restrict__ A1, const h16* __restrict__ A2,
    int strideA, int ksteps,
    const h16* __restrict__ Wt, const float* __restrict__ bias,
    float* __restrict__ outF, h16* __restrict__ out16, int n) {
    int tid = threadIdx.x;
    int wave = tid >> 6, lane = tid & 63;
    int nq = lane & 15, quad = lane >> 4;
    int row0 = (blockIdx.x * 4 + wave) * 32;
    const h16* Aseg[3] = {A0, A1, A2};

    float4v acc[2][NT];
#pragma unroll
    for (int r = 0; r < 2; r++)
#pragma unroll
        for (int t = 0; t < NT; t++) acc[r][t] = (float4v)0.f;

    for (int seg = 0; seg < 3; ++seg) {
        const h16* Ab = Aseg[seg] + (size_t)(row0 + nq) * strideA + quad * 8;
        const h16* Bb = Wt + (size_t)seg * ksteps * 208 * 32 + (size_t)nq * 32 + quad * 8;
        for (int ks = 0; ks < ksteps; ++ks) {
            half8 af0 = *(const half8*)(Ab + ks * 32);
            half8 af1 = *(const half8*)(Ab + 16 * strideA + ks * 32);
            const h16* Bk = Bb + (size_t)ks * 208 * 32;
#pragma unroll
            for (int t = 0; t < NT; ++t) {
                half8 bf = *(const half8*)(Bk + t * 16 * 32);
                acc[0][t] = __builtin_amdgcn_mfma_f32_16x16x32_f16(af0, bf, acc[0][t], 0, 0, 0);
                acc[1][t] = __builtin_amdgcn_mfma_f32_16x16x32_f16(af1, bf, acc[1][t], 0, 0, 0);
            }
        }
    }
#pragma unroll
    for (int r = 0; r < 2; ++r) {
        int rowb = row0 + r * 16 + quad * 4;
#pragma unroll
        for (int t = 0; t < NT; ++t) {
            int col = t * 16 + nq;
            if (col >= HD) continue;
            float bj = bias[col];
#pragma unroll
            for (int g = 0; g < 4; ++g) {
                int row = rowb + g;
                if (row < n) {
                    float v = fmaxf(acc[r][t][g] + bj, 0.0f);
                    if (outF)  outF[(size_t)row * HD + col] = v;
                    if (out16) out16[(size_t)row * KPAD + col] = (h16)v;
                }
            }
        }
    }
}

// ---------- fused segmented pool (mean+max) + FC + log_softmax: one block per graph ----------
__global__ __launch_bounds__(256) void k_pool_fc(
    const float* __restrict__ Hf, const int* __restrict__ gstart,
    const float* __restrict__ fcw, const float* __restrict__ fcb,
    float* __restrict__ out) {
    __shared__ float red[8];
    int g = blockIdx.x;
    int j = threadIdx.x;
    int i0 = gstart[g], i1 = gstart[g + 1];
    float s0 = 0.f, s1 = 0.f, s2 = 0.f, s3 = 0.f, mx = 0.f;   // post-ReLU: max >= 0
    if (j < HD) {
        int i = i0;
        for (; i + 3 < i1; i += 4) {
            float v0 = Hf[(size_t)i * HD + j];
            float v1 = Hf[(size_t)(i + 1) * HD + j];
            float v2 = Hf[(size_t)(i + 2) * HD + j];
            float v3 = Hf[(size_t)(i + 3) * HD + j];
            s0 += v0; s1 += v1; s2 += v2; s3 += v3;
            mx = fmaxf(mx, fmaxf(fmaxf(v0, v1), fmaxf(v2, v3)));
        }
        for (; i < i1; ++i) {
            float v = Hf[(size_t)i * HD + j];
            s0 += v; mx = fmaxf(mx, v);
        }
    }
    float cntf = (float)(i1 - i0);
    float mean = (s0 + s1 + s2 + s3) / fmaxf(cntf, 1.f);
    float p0 = 0.f, p1 = 0.f;
    if (j < HD) {
        p0 = mean * fcw[2 * j]     + mx * fcw[2 * (HD + j)];
        p1 = mean * fcw[2 * j + 1] + mx * fcw[2 * (HD + j) + 1];
    }
#pragma unroll
    for (int o = 32; o > 0; o >>= 1) {
        p0 += __shfl_down(p0, o);
        p1 += __shfl_down(p1, o);
    }
    int wave = j >> 6, lane = j & 63;
    if (lane == 0) { red[wave * 2] = p0; red[wave * 2 + 1] = p1; }
    __syncthreads();
    if (j == 0) {
        float z0 = red[0] + red[2] + red[4] + red[6] + fcb[0];
        float z1 = red[1] + red[3] + red[5] + red[7] + fcb[1];
        float m = fmaxf(z0, z1);
        float lse = m + logf(expf(z0 - m) + expf(z1 - m));
        out[g * 2 + 0] = z0 - lse;
        out[g * 2 + 1] = z1 - lse;
    }
}

extern "C" void kernel_launch(void* const* d_in, const int* in_sizes, int n_in,
                              void* d_out, int out_size, void* d_ws, size_t ws_size,
                              hipStream_t stream) {
    const float* x     = (const float*)d_in[0];
    const int*   edge  = (const int*)d_in[1];
    const int*   batch = (const int*)d_in[2];
    const float* lmax  = (const float*)d_in[3];
    const float* W1 = (const float*)d_in[4];  const float* b1 = (const float*)d_in[5];
    const float* W2 = (const float*)d_in[6];  const float* b2 = (const float*)d_in[7];
    const float* W3 = (const float*)d_in[8];  const float* b3 = (const float*)d_in[9];
    const float* W4 = (const float*)d_in[10]; const float* b4 = (const float*)d_in[11];
    const float* fcw = (const float*)d_in[12]; const float* fcb = (const float*)d_in[13];
    float* out = (float*)d_out;

    const int n = NN, E = NE;
    const int* src = edge;
    const int* dst = edge + E;

    // workspace layout (float units, each buffer 16B-aligned)
    float* ws = (float*)d_ws;
    size_t off = 0;
    auto alloc = [&](size_t nfloats) { float* p = ws + off; off += (nfloats + 3) & ~(size_t)3; return p; };
    float* dis    = alloc(NN);
    float* diag   = alloc(NN);
    int*   cntd   = (int*)alloc(NN);
    int*   rowst  = (int*)alloc(NN);
    int*   fill   = (int*)alloc(NN);
    int*   bsum   = (int*)alloc(SCAN_B);
    int*   csrs   = (int*)alloc(NE);
    float* csrw   = alloc(NE);
    int*   gstart = (int*)alloc(NG + 1);
    float* H      = alloc((size_t)MP * HD);               // f32 final-layer features (pool)
    h16*   x16    = (h16*)alloc((size_t)MP * FIN / 2);    // fp16 x
    h16*   hi0    = (h16*)alloc((size_t)MP * KPAD / 2);   // fp16 Tx0 (in-place per layer)
    h16*   hi1    = (h16*)alloc((size_t)MP * KPAD / 2);   // fp16 Tx1
    h16*   hi2    = (h16*)alloc((size_t)MP * KPAD / 2);   // fp16 Tx2
    const int WSZ0 = 3 * 2 * 208 * 32;                    // layer 0 (fin=64, ksteps=2)
    const int WSZ  = 3 * 7 * 208 * 32;                    // layers 1-3 (fin=200, ksteps=7)
    h16* wt0 = (h16*)alloc(WSZ0 / 2);
    h16* wt1 = (h16*)alloc(WSZ / 2);
    h16* wt2 = (h16*)alloc(WSZ / 2);
    h16* wt3 = (h16*)alloc(WSZ / 2);

    dim3 blk(256);
    int gE = (E + 255) / 256;
    int gN = (n + 255) / 256;
    int gScan = (n + SCAN_B - 1) / SCAN_B;
    int gN32 = (n + 31) / 32;     // 32 nodes per block (8-lane groups)
    int gGemm = MP / 128;         // 391 blocks, 4 waves x 32 rows

    // --- W pre-transpose (L2-resident fp16 fragments) + x fp16 + bounds ---
    k_wprep<<<(WSZ0 + 255) / 256, blk, 0, stream>>>(W1, wt0, FIN, 2, WSZ0);
    k_wprep<<<(WSZ + 255) / 256, blk, 0, stream>>>(W2, wt1, HD, 7, WSZ);
    k_wprep<<<(WSZ + 255) / 256, blk, 0, stream>>>(W3, wt2, HD, 7, WSZ);
    k_wprep<<<(WSZ + 255) / 256, blk, 0, stream>>>(W4, wt3, HD, 7, WSZ);
    k_split<<<(NN * FIN + 255) / 256, blk, 0, stream>>>(x, x16, NN * FIN);
    k_bounds<<<2, blk, 0, stream>>>(batch, gstart, n);
    // hi0 pads (cols 200..223) must be zero: gemm only writes cols<200
    hipMemsetAsync(hi0, 0, (size_t)MP * KPAD * 2, stream);

    // --- normalization + CSR build ---
    hipMemsetAsync(dis, 0, (size_t)NN * 4, stream);
    hipMemsetAsync(cntd, 0, (size_t)NN * 4, stream);
    hipMemsetAsync(fill, 0, (size_t)NN * 4, stream);
    k_deg<<<gE, blk, 0, stream>>>(src, dst, dis, cntd, E);
    k_node_prep<<<gN, blk, 0, stream>>>(dis, batch, lmax, diag, n);
    k_scan1<<<gScan, blk, 0, stream>>>(cntd, rowst, bsum, n);
    k_scan2<<<1, blk, 0, stream>>>(bsum, gScan);
    k_scan3<<<gScan, blk, 0, stream>>>(rowst, bsum, n);
    k_fillcsr<<<gE, blk, 0, stream>>>(src, dst, batch, lmax, dis, rowst, fill, csrs, csrw, E);

    // --- 4 Chebyshev layers ---
    const h16* wt[4] = {wt0, wt1, wt2, wt3};
    const float* bl[4] = {b1, b2, b3, b4};
    for (int l = 0; l < 4; l++) {
        int s16 = (l == 0) ? FIN : KPAD;
        int CW = (l == 0) ? 32 : 28;
        int nch = (l == 0) ? 2 : 8;
        int ksteps = (l == 0) ? 2 : 7;
        const h16* a0 = (l == 0) ? x16 : hi0;
        int gg = gN32 * nch;
        // Tx1 = prop(Tx0) -> hi1
        k_gather<<<gg, blk, 0, stream>>>(rowst, cntd, csrs, csrw, diag, a0, a0, hi1, s16, CW, nch, n, 0);
        // Tx2 = 2*prop(Tx1) - Tx0 -> hi2
        k_gather<<<gg, blk, 0, stream>>>(rowst, cntd, csrs, csrw, diag, hi1, a0, hi2, s16, CW, nch, n, 1);
        // out = relu([Tx0|Tx1|Tx2] @ W + b)
        k_gemm16<<<gGemm, blk, 0, stream>>>(a0, hi1, hi2, s16, ksteps, wt[l], bl[l],
                                            (l == 3) ? H : nullptr,
                                            (l < 3) ? hi0 : nullptr, n);
    }

    // --- fused pool + FC head (no atomics; batch is sorted) ---
    k_pool_fc<<<NG, blk, 0, stream>>>(H, gstart, fcw, fcb, out);
}